// Round 6
// baseline (249.752 us; speedup 1.0000x reference)
//
#include <hip/hip_runtime.h>

#define Bb 4
#define Tt 2048
#define Cc 1024
#define Hh 16
#define NQKV 3072
#define Mtot 8192

typedef __bf16 bf16_t;
typedef unsigned short u16;
typedef __bf16 bf16x8 __attribute__((ext_vector_type(8)));
typedef __bf16 bf16x4 __attribute__((ext_vector_type(4)));
typedef short short4v __attribute__((ext_vector_type(4)));
typedef float f32x4 __attribute__((ext_vector_type(4)));
typedef float f32x16 __attribute__((ext_vector_type(16)));
typedef unsigned uint2v __attribute__((ext_vector_type(2)));

union bfu { bf16_t b; u16 u; };
union trpair { short4v h[2]; bf16x8 v; };
union pfu { unsigned u[4]; bf16x8 v; };

#define QSCALE 0.18033688011112042f  /* 0.125 * log2(e) */

// hardware transpose read; "memory" clobber keeps it ordered after staging
#define TRD(dst, addr, OFF)                                                     \
  asm volatile("ds_read_b64_tr_b16 %0, %1 offset:" OFF                          \
               : "=v"(dst) : "v"(addr) : "memory")

__device__ __forceinline__ unsigned cvtpk(float a, float b) {
  unsigned r;
  asm("v_cvt_pk_bf16_f32 %0, %1, %2" : "=v"(r) : "v"(a), "v"(b));
  return r;
}
__device__ __forceinline__ uint2v plswap(unsigned a, unsigned b) {
  return __builtin_amdgcn_permlane32_swap(a, b, false, false);
}

#define GLOAD16(gsrc, ldst)                                                     \
  __builtin_amdgcn_global_load_lds(                                             \
      (const __attribute__((address_space(1))) unsigned int*)(gsrc),            \
      (__attribute__((address_space(3))) unsigned int*)(ldst), 16, 0, 0)

// ---------------------------------------------------------------------------
// f32 -> bf16 conversion; elements with idx < nscale multiplied by factor
// ---------------------------------------------------------------------------
__global__ __launch_bounds__(256) void cvt_f32_bf16(const float* __restrict__ s,
                                                    u16* __restrict__ d,
                                                    long nscale, float factor) {
  size_t i = ((size_t)blockIdx.x * 256 + threadIdx.x) * 8;
  const float f = ((long)i < nscale) ? factor : 1.0f;
  float4 a = *(const float4*)(s + i);
  float4 b = *(const float4*)(s + i + 4);
  bf16x8 v;
  v[0]=(bf16_t)(a.x*f); v[1]=(bf16_t)(a.y*f); v[2]=(bf16_t)(a.z*f); v[3]=(bf16_t)(a.w*f);
  v[4]=(bf16_t)(b.x*f); v[5]=(bf16_t)(b.y*f); v[6]=(bf16_t)(b.z*f); v[7]=(bf16_t)(b.w*f);
  *(bf16x8*)(d + i) = v;
}

__global__ __launch_bounds__(256) void scale_bias(const float* __restrict__ s,
                                                  float* __restrict__ d) {
  int i = blockIdx.x * 256 + threadIdx.x;  // 3072 total
  d[i] = s[i] * ((i < Cc) ? QSCALE : 1.0f);
}

// ---------------------------------------------------------------------------
// GEMM NT, bf16 inputs, m97 structure: global_load_lds w16 into LINEAR LDS,
// 2 barriers per BK=32 step. 128x128 tile, 4 waves (2x2), 64x64/wave.
// ---------------------------------------------------------------------------
template <int OUTBF16>
__global__ __launch_bounds__(256) void gemm_bf16(
    const u16* __restrict__ A, const u16* __restrict__ Bm,
    const float* __restrict__ bias, void* __restrict__ Cout,
    int M, int N, int K)
{
  __shared__ __attribute__((aligned(16))) u16 sa[128 * 32];
  __shared__ __attribute__((aligned(16))) u16 sb[128 * 32];

  const int tid  = threadIdx.x;
  const int lane = tid & 63;
  const int wid  = tid >> 6;
  const int wr   = (wid >> 1) * 64;
  const int wc   = (wid & 1) * 64;
  const int l15  = lane & 15;
  const int lh   = lane >> 4;
  const int bm   = blockIdx.x * 128;
  const int bn   = blockIdx.y * 128;

  f32x4 acc[4][4] = {};

  // staging: lane l of wave w, issue i -> row = w*32 + i*16 + (l>>2), col = (l&3)*8
  const int r0 = wid * 32 + (lane >> 2);
  const int c0 = (lane & 3) * 8;
  const u16* pa0 = A  + (size_t)(bm + r0) * K + c0;
  const u16* pb0 = Bm + (size_t)(bn + r0) * K + c0;
  u16* sA0 = sa + wid * 1024;        // wave chunk (2048 B), lane offset = lane*16B
  u16* sA1 = sa + wid * 1024 + 512;
  u16* sB0 = sb + wid * 1024;
  u16* sB1 = sb + wid * 1024 + 512;
  const size_t k16 = (size_t)16 * K;

  for (int k0 = 0; k0 < K; k0 += 32) {
    __syncthreads();                  // prev compute done; LDS reusable
    GLOAD16(pa0,       sA0);
    GLOAD16(pa0 + k16, sA1);
    GLOAD16(pb0,       sB0);
    GLOAD16(pb0 + k16, sB1);
    pa0 += 32; pb0 += 32;
    __syncthreads();                  // vmcnt(0) drain: tiles landed

    bf16x8 af[4], bfv[4];
#pragma unroll
    for (int mi = 0; mi < 4; mi++)
      af[mi] = *(const bf16x8*)&sa[(wr + mi*16 + l15) * 32 + lh * 8];
#pragma unroll
    for (int ni = 0; ni < 4; ni++)
      bfv[ni] = *(const bf16x8*)&sb[(wc + ni*16 + l15) * 32 + lh * 8];
#pragma unroll
    for (int mi = 0; mi < 4; mi++)
#pragma unroll
      for (int ni = 0; ni < 4; ni++)
        acc[mi][ni] = __builtin_amdgcn_mfma_f32_16x16x32_bf16(
            af[mi], bfv[ni], acc[mi][ni], 0, 0, 0);
  }

#pragma unroll
  for (int mi = 0; mi < 4; mi++) {
#pragma unroll
    for (int ni = 0; ni < 4; ni++) {
      const int col = bn + wc + ni*16 + l15;
      const float bs = bias[col];
#pragma unroll
      for (int r = 0; r < 4; r++) {
        const int row = bm + wr + mi*16 + lh*4 + r;
        const float val = acc[mi][ni][r] + bs;
        if (OUTBF16) {
          bfu cv; cv.b = (bf16_t)val;
          ((u16*)Cout)[(size_t)row * N + col] = cv.u;
        } else {
          ((float*)Cout)[(size_t)row * N + col] = val;
        }
      }
    }
  }
}

// ---------------------------------------------------------------------------
// Causal flash attention, T12 structure at 32x32 MFMA.
// Grid (16, B*H) = 1024 blocks (4 resident/CU); longest-first (qb = 15-bx).
// LDS (u16): K [0,4608) as [64 key][72 d-pad]; V [4608,9216) as [64 key][72].
// S^T = mfma(K,Q): q = lane&31, keys = (reg&3)+8*(reg>>2)+4*(lane>>5) (+32kb).
// Softmax per-lane scalar (m,l); P packed in-register (cvt_pk + permlane32).
// O^T = mfma(V^T via tr-reads, P).  Q prescaled by 0.125*log2e (in weights).
// ---------------------------------------------------------------------------
#define V0u 4608
__global__ __launch_bounds__(256) void attn_kernel(
    const u16* __restrict__ qkv, u16* __restrict__ y)
{
  __shared__ __attribute__((aligned(16))) u16 smem[9216];

  const int tid  = threadIdx.x;
  const int lane = tid & 63;
  const int w    = tid >> 6;
  const int l31  = lane & 31;
  const int hh   = lane >> 5;
  const int l15  = lane & 15;
  const int lh   = lane >> 4;
  const int bh   = blockIdx.y;
  const int b    = bh >> 4;
  const int head = bh & 15;

  const size_t rowbase = (size_t)b * Tt * NQKV;

  const int skey = tid >> 2;
  const int sp   = tid & 3;
  const u16* kbase = qkv + rowbase + 1024 + head*64 + sp*16;
  const u16* vbase = qkv + rowbase + 2048 + head*64 + sp*16;

  // V^T tr-read lane address (bytes)
  const unsigned smemB = (unsigned)(size_t)(&smem[0]);
  const unsigned vaddr = smemB + 2*V0u
      + ((lh>>1)*8 + (l15>>2))*144 + (lh&1)*32 + (l15&3)*8;

  const int qb    = 15 - (int)blockIdx.x;   // longest blocks launch first
  const int qbase = qb * 128;
  const int qw    = qbase + w * 32;
  const int qi    = qw + l31;               // this lane's q row
  const int ktiles = 2*qb + 2;

  // Q fragments (B operand): lane holds Q[qi][m*16 + hh*8 + j]
  bf16x8 qfrag[4];
#pragma unroll
  for (int m = 0; m < 4; ++m)
    qfrag[m] = *(const bf16x8*)(qkv + rowbase + (size_t)qi * NQKV
                                + head*64 + m*16 + hh*8);

  f32x16 o0 = {}, o1 = {};                  // O^T: d 0..31 / d 32..63
  float m_run = -1e30f, l_part = 0.0f;

  uint4 kr0 = *(const uint4*)(kbase + (size_t)skey * NQKV);
  uint4 kr1 = *(const uint4*)(kbase + (size_t)skey * NQKV + 8);
  uint4 vr0 = *(const uint4*)(vbase + (size_t)skey * NQKV);
  uint4 vr1 = *(const uint4*)(vbase + (size_t)skey * NQKV + 8);

  for (int kt = 0; kt < ktiles; ++kt) {
    __syncthreads();
    *(uint4*)&smem[skey*72 + sp*16]           = kr0;
    *(uint4*)&smem[skey*72 + sp*16 + 8]       = kr1;
    *(uint4*)&smem[V0u + skey*72 + sp*16]     = vr0;
    *(uint4*)&smem[V0u + skey*72 + sp*16 + 8] = vr1;
    __syncthreads();

    if (kt + 1 < ktiles) {   // T14: issue next tile's loads before compute
      const u16* kp = kbase + (size_t)((kt+1)*64 + skey) * NQKV;
      const u16* vp = vbase + (size_t)((kt+1)*64 + skey) * NQKV;
      kr0 = *(const uint4*)kp; kr1 = *(const uint4*)(kp + 8);
      vr0 = *(const uint4*)vp; vr1 = *(const uint4*)(vp + 8);
    }

    if (kt*64 <= qw + 31) {
      // ---- S^T = K Q^T : two 32-key blocks ----
      f32x16 s0 = {}, s1 = {};
#pragma unroll
      for (int m = 0; m < 4; ++m) {
        bf16x8 k0 = *(const bf16x8*)&smem[(l31)*72      + m*16 + hh*8];
        bf16x8 k1 = *(const bf16x8*)&smem[(32 + l31)*72 + m*16 + hh*8];
        s0 = __builtin_amdgcn_mfma_f32_32x32x16_bf16(k0, qfrag[m], s0, 0,0,0);
        s1 = __builtin_amdgcn_mfma_f32_32x32x16_bf16(k1, qfrag[m], s1, 0,0,0);
      }

      // ---- causal mask (diagonal region only) ----
      if (kt*64 + 63 > qw) {
        const int kb0 = kt*64;
#pragma unroll
        for (int r = 0; r < 16; ++r) {
          const int crow = (r&3) + 8*(r>>2) + 4*hh;
          if (kb0 + crow > qi)      s0[r] = -1e30f;
          if (kb0 + 32 + crow > qi) s1[r] = -1e30f;
        }
      }

      // ---- per-lane softmax: in-lane max + one permlane swap ----
      float rm = s0[0];
#pragma unroll
      for (int r = 1; r < 16; ++r) rm = fmaxf(rm, s0[r]);
#pragma unroll
      for (int r = 0; r < 16; ++r) rm = fmaxf(rm, s1[r]);
      {
        uint2v t = plswap(__float_as_uint(rm), __float_as_uint(rm));
        rm = fmaxf(__uint_as_float(t[0]), __uint_as_float(t[1]));
      }
      if (__any(rm > m_run + 8.0f)) {     // defer-max THR=8 (log2 units)
        const float mn = fmaxf(m_run, rm);
        const float al = exp2f(m_run - mn);
        m_run = mn; l_part *= al;
#pragma unroll
        for (int r = 0; r < 16; ++r) { o0[r] *= al; o1[r] *= al; }
      }

      // ---- exp2 + in-register P pack (T12) ----
      pfu pf0, pf1, pf2, pf3;
      {
        float pe[16];
#pragma unroll
        for (int r = 0; r < 16; ++r) { pe[r] = exp2f(s0[r] - m_run); l_part += pe[r]; }
        unsigned a0 = cvtpk(pe[0],pe[1]),  a1 = cvtpk(pe[2],pe[3]);
        unsigned a2 = cvtpk(pe[4],pe[5]),  a3 = cvtpk(pe[6],pe[7]);
        uint2v x1 = plswap(a0, a2), x2 = plswap(a1, a3);
        pf0.u[0]=x1[0]; pf0.u[1]=x2[0]; pf0.u[2]=x1[1]; pf0.u[3]=x2[1];
        unsigned b0 = cvtpk(pe[8],pe[9]),  b1 = cvtpk(pe[10],pe[11]);
        unsigned b2 = cvtpk(pe[12],pe[13]), b3 = cvtpk(pe[14],pe[15]);
        uint2v x3 = plswap(b0, b2), x4 = plswap(b1, b3);
        pf1.u[0]=x3[0]; pf1.u[1]=x4[0]; pf1.u[2]=x3[1]; pf1.u[3]=x4[1];
      }
      {
        float pe[16];
#pragma unroll
        for (int r = 0; r < 16; ++r) { pe[r] = exp2f(s1[r] - m_run); l_part += pe[r]; }
        unsigned a0 = cvtpk(pe[0],pe[1]),  a1 = cvtpk(pe[2],pe[3]);
        unsigned a2 = cvtpk(pe[4],pe[5]),  a3 = cvtpk(pe[6],pe[7]);
        uint2v x1 = plswap(a0, a2), x2 = plswap(a1, a3);
        pf2.u[0]=x1[0]; pf2.u[1]=x2[0]; pf2.u[2]=x1[1]; pf2.u[3]=x2[1];
        unsigned b0 = cvtpk(pe[8],pe[9]),  b1 = cvtpk(pe[10],pe[11]);
        unsigned b2 = cvtpk(pe[12],pe[13]), b3 = cvtpk(pe[14],pe[15]);
        uint2v x3 = plswap(b0, b2), x4 = plswap(b1, b3);
        pf3.u[0]=x3[0]; pf3.u[1]=x4[0]; pf3.u[2]=x3[1]; pf3.u[3]=x4[1];
      }

      // ---- O^T += V^T P : 16 tr-reads, then 8 MFMAs ----
      short4v ta0,tb0,ta1,tb1,ta2,tb2,ta3,tb3,ta4,tb4,ta5,tb5,ta6,tb6,ta7,tb7;
      TRD(ta0, vaddr, "0");    TRD(tb0, vaddr, "576");   // c0 d2=0
      TRD(ta1, vaddr, "64");   TRD(tb1, vaddr, "640");   // c0 d2=1
      TRD(ta2, vaddr, "2304"); TRD(tb2, vaddr, "2880");  // c1 d2=0
      TRD(ta3, vaddr, "2368"); TRD(tb3, vaddr, "2944");  // c1 d2=1
      TRD(ta4, vaddr, "4608"); TRD(tb4, vaddr, "5184");  // c2 d2=0
      TRD(ta5, vaddr, "4672"); TRD(tb5, vaddr, "5248");  // c2 d2=1
      TRD(ta6, vaddr, "6912"); TRD(tb6, vaddr, "7488");  // c3 d2=0
      TRD(ta7, vaddr, "6976"); TRD(tb7, vaddr, "7552");  // c3 d2=1
      asm volatile("s_waitcnt lgkmcnt(0)" ::: "memory");
      __builtin_amdgcn_sched_barrier(0);
      trpair v00,v01,v10,v11,v20,v21,v30,v31;
      v00.h[0]=ta0; v00.h[1]=tb0;  v01.h[0]=ta1; v01.h[1]=tb1;
      v10.h[0]=ta2; v10.h[1]=tb2;  v11.h[0]=ta3; v11.h[1]=tb3;
      v20.h[0]=ta4; v20.h[1]=tb4;  v21.h[0]=ta5; v21.h[1]=tb5;
      v30.h[0]=ta6; v30.h[1]=tb6;  v31.h[0]=ta7; v31.h[1]=tb7;
      o0 = __builtin_amdgcn_mfma_f32_32x32x16_bf16(v00.v, pf0.v, o0, 0,0,0);
      o1 = __builtin_amdgcn_mfma_f32_32x32x16_bf16(v01.v, pf0.v, o1, 0,0,0);
      o0 = __builtin_amdgcn_mfma_f32_32x32x16_bf16(v10.v, pf1.v, o0, 0,0,0);
      o1 = __builtin_amdgcn_mfma_f32_32x32x16_bf16(v11.v, pf1.v, o1, 0,0,0);
      o0 = __builtin_amdgcn_mfma_f32_32x32x16_bf16(v20.v, pf2.v, o0, 0,0,0);
      o1 = __builtin_amdgcn_mfma_f32_32x32x16_bf16(v21.v, pf2.v, o1, 0,0,0);
      o0 = __builtin_amdgcn_mfma_f32_32x32x16_bf16(v30.v, pf3.v, o0, 0,0,0);
      o1 = __builtin_amdgcn_mfma_f32_32x32x16_bf16(v31.v, pf3.v, o1, 0,0,0);
    }
  }

  // ---- epilogue ----
  {
    uint2v t = plswap(__float_as_uint(l_part), __float_as_uint(l_part));
    l_part = __uint_as_float(t[0]) + __uint_as_float(t[1]);
  }
  const float inv = 1.0f / l_part;

  __syncthreads();   // all waves done with K/V before scratch reuse
#pragma unroll
  for (int k4 = 0; k4 < 4; ++k4) {
    bf16x4 pa, pb;
#pragma unroll
    for (int j = 0; j < 4; ++j) {
      pa[j] = (bf16_t)(o0[4*k4 + j] * inv);
      pb[j] = (bf16_t)(o1[4*k4 + j] * inv);
    }
    *(bf16x4*)&smem[w*2304 + l31*72 +      8*k4 + 4*hh] = pa;
    *(bf16x4*)&smem[w*2304 + l31*72 + 32 + 8*k4 + 4*hh] = pb;
  }
  u16* yp = y + ((size_t)(b*Tt + qi)) * Cc + head*64;
#pragma unroll
  for (int p = 0; p < 4; ++p) {
    bf16x8 row = *(const bf16x8*)&smem[w*2304 + l31*72 + p*16 + hh*8];
    *(bf16x8*)(yp + p*16 + hh*8) = row;
  }
}

// ---------------------------------------------------------------------------
extern "C" void kernel_launch(void* const* d_in, const int* in_sizes, int n_in,
                              void* d_out, int out_size, void* d_ws, size_t ws_size,
                              hipStream_t stream) {
  const float* x      = (const float*)d_in[0];
  const float* w_attn = (const float*)d_in[1];
  const float* b_attn = (const float*)d_in[2];
  const float* w_proj = (const float*)d_in[3];
  const float* b_proj = (const float*)d_in[4];
  float* out = (float*)d_out;

  char* ws = (char*)d_ws;
  u16*   xb    = (u16*)(ws + 0);          // 16 MB
  u16*   wab   = (u16*)(ws + 16777216);   // 6 MB
  u16*   wpb   = (u16*)(ws + 23068672);   // 2 MB
  u16*   qkvb  = (u16*)(ws + 25165824);   // 48 MB
  u16*   yb    = (u16*)(ws + 75497472);   // 16 MB
  float* sbias = (float*)(ws + 92274688); // 12 KB

  // convert inputs to bf16; fold 0.125*log2e into Wq rows and bq
  cvt_f32_bf16<<<4096, 256, 0, stream>>>(x,      xb,  0, 1.0f);
  cvt_f32_bf16<<<1536, 256, 0, stream>>>(w_attn, wab, (long)Cc*Cc, QSCALE);
  cvt_f32_bf16<<<512,  256, 0, stream>>>(w_proj, wpb, 0, 1.0f);
  scale_bias<<<12, 256, 0, stream>>>(b_attn, sbias);

  // 1) QKV projection (bf16 out, q pre-scaled)
  gemm_bf16<1><<<dim3(Mtot/128, NQKV/128), 256, 0, stream>>>(
      xb, wab, sbias, (void*)qkvb, Mtot, NQKV, Cc);

  // 2) causal attention (bf16 y)
  attn_kernel<<<dim3(16, Bb*Hh), 256, 0, stream>>>(qkvb, yb);

  // 3) output projection (f32 out)
  gemm_bf16<0><<<dim3(Mtot/128, Cc/128), 256, 0, stream>>>(
      yb, wpb, b_proj, (void*)out, Mtot, Cc, Cc);
}

// Round 7
// 204.121 us; speedup vs baseline: 1.2235x; 1.2235x over previous
//
#include <hip/hip_runtime.h>

#define Bb 4
#define Tt 2048
#define Cc 1024
#define Hh 16
#define NQKV 3072
#define Mtot 8192

typedef __bf16 bf16_t;
typedef unsigned short u16;
typedef __bf16 bf16x8 __attribute__((ext_vector_type(8)));
typedef __bf16 bf16x4 __attribute__((ext_vector_type(4)));
typedef short short4v __attribute__((ext_vector_type(4)));
typedef float f32x4 __attribute__((ext_vector_type(4)));
typedef float f32x16 __attribute__((ext_vector_type(16)));
typedef unsigned uint2v __attribute__((ext_vector_type(2)));

union bfu { bf16_t b; u16 u; };
union trpair { short4v h[2]; bf16x8 v; };
union pfu { unsigned u[4]; bf16x8 v; };

#define QSCALE 0.18033688011112042f  /* 0.125 * log2(e) */

// hardware transpose read; "memory" clobber keeps it ordered after staging
#define TRD(dst, addr, OFF)                                                     \
  asm volatile("ds_read_b64_tr_b16 %0, %1 offset:" OFF                          \
               : "=v"(dst) : "v"(addr) : "memory")

__device__ __forceinline__ unsigned cvtpk(float a, float b) {
  unsigned r;
  asm("v_cvt_pk_bf16_f32 %0, %1, %2" : "=v"(r) : "v"(a), "v"(b));
  return r;
}
__device__ __forceinline__ uint2v plswap(unsigned a, unsigned b) {
  return __builtin_amdgcn_permlane32_swap(a, b, false, false);
}

#define GLOAD16(gsrc, ldst)                                                     \
  __builtin_amdgcn_global_load_lds(                                             \
      (const __attribute__((address_space(1))) unsigned int*)(gsrc),            \
      (__attribute__((address_space(3))) unsigned int*)(ldst), 16, 0, 0)

// ---------------------------------------------------------------------------
// f32 -> bf16 conversion; elements with idx < nscale multiplied by factor
// ---------------------------------------------------------------------------
__global__ __launch_bounds__(256) void cvt_f32_bf16(const float* __restrict__ s,
                                                    u16* __restrict__ d,
                                                    long nscale, float factor) {
  size_t i = ((size_t)blockIdx.x * 256 + threadIdx.x) * 8;
  const float f = ((long)i < nscale) ? factor : 1.0f;
  float4 a = *(const float4*)(s + i);
  float4 b = *(const float4*)(s + i + 4);
  bf16x8 v;
  v[0]=(bf16_t)(a.x*f); v[1]=(bf16_t)(a.y*f); v[2]=(bf16_t)(a.z*f); v[3]=(bf16_t)(a.w*f);
  v[4]=(bf16_t)(b.x*f); v[5]=(bf16_t)(b.y*f); v[6]=(bf16_t)(b.z*f); v[7]=(bf16_t)(b.w*f);
  *(bf16x8*)(d + i) = v;
}

__global__ __launch_bounds__(256) void scale_bias(const float* __restrict__ s,
                                                  float* __restrict__ d) {
  int i = blockIdx.x * 256 + threadIdx.x;  // 3072 total
  d[i] = s[i] * ((i < Cc) ? QSCALE : 1.0f);
}

// ---------------------------------------------------------------------------
// GEMM NT, bf16 inputs, m97 structure: global_load_lds w16 into LINEAR LDS,
// 2 barriers per BK=32 step. 128x128 tile, 4 waves (2x2), 64x64/wave.
// ---------------------------------------------------------------------------
template <int OUTBF16>
__global__ __launch_bounds__(256) void gemm_bf16(
    const u16* __restrict__ A, const u16* __restrict__ Bm,
    const float* __restrict__ bias, void* __restrict__ Cout,
    int M, int N, int K)
{
  __shared__ __attribute__((aligned(16))) u16 sa[128 * 32];
  __shared__ __attribute__((aligned(16))) u16 sb[128 * 32];

  const int tid  = threadIdx.x;
  const int lane = tid & 63;
  const int wid  = tid >> 6;
  const int wr   = (wid >> 1) * 64;
  const int wc   = (wid & 1) * 64;
  const int l15  = lane & 15;
  const int lh   = lane >> 4;
  const int bm   = blockIdx.x * 128;
  const int bn   = blockIdx.y * 128;

  f32x4 acc[4][4] = {};

  const int r0 = wid * 32 + (lane >> 2);
  const int c0 = (lane & 3) * 8;
  const u16* pa0 = A  + (size_t)(bm + r0) * K + c0;
  const u16* pb0 = Bm + (size_t)(bn + r0) * K + c0;
  u16* sA0 = sa + wid * 1024;
  u16* sA1 = sa + wid * 1024 + 512;
  u16* sB0 = sb + wid * 1024;
  u16* sB1 = sb + wid * 1024 + 512;
  const size_t k16 = (size_t)16 * K;

  for (int k0 = 0; k0 < K; k0 += 32) {
    __syncthreads();
    GLOAD16(pa0,       sA0);
    GLOAD16(pa0 + k16, sA1);
    GLOAD16(pb0,       sB0);
    GLOAD16(pb0 + k16, sB1);
    pa0 += 32; pb0 += 32;
    __syncthreads();

    bf16x8 af[4], bfv[4];
#pragma unroll
    for (int mi = 0; mi < 4; mi++)
      af[mi] = *(const bf16x8*)&sa[(wr + mi*16 + l15) * 32 + lh * 8];
#pragma unroll
    for (int ni = 0; ni < 4; ni++)
      bfv[ni] = *(const bf16x8*)&sb[(wc + ni*16 + l15) * 32 + lh * 8];
#pragma unroll
    for (int mi = 0; mi < 4; mi++)
#pragma unroll
      for (int ni = 0; ni < 4; ni++)
        acc[mi][ni] = __builtin_amdgcn_mfma_f32_16x16x32_bf16(
            af[mi], bfv[ni], acc[mi][ni], 0, 0, 0);
  }

#pragma unroll
  for (int mi = 0; mi < 4; mi++) {
#pragma unroll
    for (int ni = 0; ni < 4; ni++) {
      const int col = bn + wc + ni*16 + l15;
      const float bs = bias[col];
#pragma unroll
      for (int r = 0; r < 4; r++) {
        const int row = bm + wr + mi*16 + lh*4 + r;
        const float val = acc[mi][ni][r] + bs;
        if (OUTBF16) {
          bfu cv; cv.b = (bf16_t)val;
          ((u16*)Cout)[(size_t)row * N + col] = cv.u;
        } else {
          ((float*)Cout)[(size_t)row * N + col] = val;
        }
      }
    }
  }
}

// ---------------------------------------------------------------------------
// Causal flash attention, T12 structure at 32x32 MFMA + double-buffered K/V.
// Grid (8, B*H): block handles q-tile pair {x, 15-x} (uniform 34 k-tiles).
// LDS: 2 buffers of (K [64][72] + V [64][72]) = 36 KB; ONE barrier per tile.
// S^T = mfma(K,Q): q = lane&31, keys = (reg&3)+8*(reg>>2)+4*(lane>>5) (+32kb).
// Softmax per-lane scalar (m,l); P packed in-register (cvt_pk + permlane32).
// O^T = mfma(V^T via tr-reads, P).  Q prescaled by 0.125*log2e (in weights).
// ---------------------------------------------------------------------------
#define HBUF 9216   /* u16 per buffer */

#define LOADT(t, K0, K1, V0, V1) do {                                           \
  const u16* kp_ = kbase + (size_t)((t)*64 + skey) * NQKV;                      \
  const u16* vp_ = vbase + (size_t)((t)*64 + skey) * NQKV;                      \
  K0 = *(const uint4*)kp_; K1 = *(const uint4*)(kp_ + 8);                       \
  V0 = *(const uint4*)vp_; V1 = *(const uint4*)(vp_ + 8);                       \
} while (0)

#define STAGE(bofs, K0, K1, V0, V1) do {                                        \
  *(uint4*)&smem[(bofs) + skey*72 + sp*16]            = K0;                     \
  *(uint4*)&smem[(bofs) + skey*72 + sp*16 + 8]        = K1;                     \
  *(uint4*)&smem[(bofs) + 4608 + skey*72 + sp*16]     = V0;                     \
  *(uint4*)&smem[(bofs) + 4608 + skey*72 + sp*16 + 8] = V1;                     \
} while (0)

__global__ __launch_bounds__(256) void attn_kernel(
    const u16* __restrict__ qkv, u16* __restrict__ y)
{
  __shared__ __attribute__((aligned(16))) u16 smem[2 * HBUF];  // 36 KB

  const int tid  = threadIdx.x;
  const int lane = tid & 63;
  const int w    = tid >> 6;
  const int l31  = lane & 31;
  const int hh   = lane >> 5;
  const int l15  = lane & 15;
  const int lh   = lane >> 4;
  const int bh   = blockIdx.y;
  const int b    = bh >> 4;
  const int head = bh & 15;

  const size_t rowbase = (size_t)b * Tt * NQKV;

  const int skey = tid >> 2;
  const int sp   = tid & 3;
  const u16* kbase = qkv + rowbase + 1024 + head*64 + sp*16;
  const u16* vbase = qkv + rowbase + 2048 + head*64 + sp*16;

  // V^T tr-read lane addresses (bytes), one per buffer
  const unsigned smemB = (unsigned)(size_t)(&smem[0]);
  const unsigned trl   = ((lh>>1)*8 + (l15>>2))*144 + (lh&1)*32 + (l15&3)*8;
  const unsigned vaddr0 = smemB + 9216 + trl;           // buf0 V @ byte 9216
  const unsigned vaddr1 = smemB + 18432 + 9216 + trl;   // buf1 V

  for (int half = 0; half < 2; ++half) {
    const int qb    = half ? (15 - (int)blockIdx.x) : (int)blockIdx.x;
    const int qbase = qb * 128;
    const int qw    = qbase + w * 32;
    const int qi    = qw + l31;            // this lane's q row
    const int ktiles = 2*qb + 2;

    // Q fragments (B operand): lane holds Q[qi][m*16 + hh*8 + j]
    bf16x8 qfrag[4];
#pragma unroll
    for (int m = 0; m < 4; ++m)
      qfrag[m] = *(const bf16x8*)(qkv + rowbase + (size_t)qi * NQKV
                                  + head*64 + m*16 + hh*8);

    f32x16 o0 = {}, o1 = {};               // O^T: d 0..31 / d 32..63
    float m_run = -1e30f, l_part = 0.0f;

    auto compute_tile = [&](int bofs, int kt, unsigned vaddr_) {
      if (kt*64 > qw + 31) return;
      // ---- S^T = K Q^T ----
      f32x16 s0 = {}, s1 = {};
      __builtin_amdgcn_s_setprio(1);
#pragma unroll
      for (int m = 0; m < 4; ++m) {
        bf16x8 k0 = *(const bf16x8*)&smem[bofs + (l31)*72      + m*16 + hh*8];
        bf16x8 k1 = *(const bf16x8*)&smem[bofs + (32 + l31)*72 + m*16 + hh*8];
        s0 = __builtin_amdgcn_mfma_f32_32x32x16_bf16(k0, qfrag[m], s0, 0,0,0);
        s1 = __builtin_amdgcn_mfma_f32_32x32x16_bf16(k1, qfrag[m], s1, 0,0,0);
      }
      __builtin_amdgcn_s_setprio(0);

      // ---- causal mask (diagonal region only) ----
      if (kt*64 + 63 > qw) {
        const int kb0 = kt*64;
#pragma unroll
        for (int r = 0; r < 16; ++r) {
          const int crow = (r&3) + 8*(r>>2) + 4*hh;
          if (kb0 + crow > qi)      s0[r] = -1e30f;
          if (kb0 + 32 + crow > qi) s1[r] = -1e30f;
        }
      }

      // ---- per-lane softmax: in-lane max + one permlane swap ----
      float rm = s0[0];
#pragma unroll
      for (int r = 1; r < 16; ++r) rm = fmaxf(rm, s0[r]);
#pragma unroll
      for (int r = 0; r < 16; ++r) rm = fmaxf(rm, s1[r]);
      {
        uint2v t = plswap(__float_as_uint(rm), __float_as_uint(rm));
        rm = fmaxf(__uint_as_float(t[0]), __uint_as_float(t[1]));
      }
      if (__any(rm > m_run + 8.0f)) {      // defer-max THR=8 (log2 units)
        const float mn = fmaxf(m_run, rm);
        const float al = exp2f(m_run - mn);
        m_run = mn; l_part *= al;
#pragma unroll
        for (int r = 0; r < 16; ++r) { o0[r] *= al; o1[r] *= al; }
      }

      // ---- exp2 + in-register P pack (T12) ----
      pfu pf0, pf1, pf2, pf3;
      {
        float pe[16];
#pragma unroll
        for (int r = 0; r < 16; ++r) { pe[r] = exp2f(s0[r] - m_run); l_part += pe[r]; }
        unsigned a0 = cvtpk(pe[0],pe[1]),  a1 = cvtpk(pe[2],pe[3]);
        unsigned a2 = cvtpk(pe[4],pe[5]),  a3 = cvtpk(pe[6],pe[7]);
        uint2v x1 = plswap(a0, a2), x2 = plswap(a1, a3);
        pf0.u[0]=x1[0]; pf0.u[1]=x2[0]; pf0.u[2]=x1[1]; pf0.u[3]=x2[1];
        unsigned b0 = cvtpk(pe[8],pe[9]),  b1 = cvtpk(pe[10],pe[11]);
        unsigned b2 = cvtpk(pe[12],pe[13]), b3 = cvtpk(pe[14],pe[15]);
        uint2v x3 = plswap(b0, b2), x4 = plswap(b1, b3);
        pf1.u[0]=x3[0]; pf1.u[1]=x4[0]; pf1.u[2]=x3[1]; pf1.u[3]=x4[1];
      }
      {
        float pe[16];
#pragma unroll
        for (int r = 0; r < 16; ++r) { pe[r] = exp2f(s1[r] - m_run); l_part += pe[r]; }
        unsigned a0 = cvtpk(pe[0],pe[1]),  a1 = cvtpk(pe[2],pe[3]);
        unsigned a2 = cvtpk(pe[4],pe[5]),  a3 = cvtpk(pe[6],pe[7]);
        uint2v x1 = plswap(a0, a2), x2 = plswap(a1, a3);
        pf2.u[0]=x1[0]; pf2.u[1]=x2[0]; pf2.u[2]=x1[1]; pf2.u[3]=x2[1];
        unsigned b0 = cvtpk(pe[8],pe[9]),  b1 = cvtpk(pe[10],pe[11]);
        unsigned b2 = cvtpk(pe[12],pe[13]), b3 = cvtpk(pe[14],pe[15]);
        uint2v x3 = plswap(b0, b2), x4 = plswap(b1, b3);
        pf3.u[0]=x3[0]; pf3.u[1]=x4[0]; pf3.u[2]=x3[1]; pf3.u[3]=x4[1];
      }

      // ---- O^T += V^T P : 16 tr-reads, then 8 MFMAs ----
      short4v ta0,tb0,ta1,tb1,ta2,tb2,ta3,tb3,ta4,tb4,ta5,tb5,ta6,tb6,ta7,tb7;
      TRD(ta0, vaddr_, "0");    TRD(tb0, vaddr_, "576");   // c0 d2=0
      TRD(ta1, vaddr_, "64");   TRD(tb1, vaddr_, "640");   // c0 d2=1
      TRD(ta2, vaddr_, "2304"); TRD(tb2, vaddr_, "2880");  // c1 d2=0
      TRD(ta3, vaddr_, "2368"); TRD(tb3, vaddr_, "2944");  // c1 d2=1
      TRD(ta4, vaddr_, "4608"); TRD(tb4, vaddr_, "5184");  // c2 d2=0
      TRD(ta5, vaddr_, "4672"); TRD(tb5, vaddr_, "5248");  // c2 d2=1
      TRD(ta6, vaddr_, "6912"); TRD(tb6, vaddr_, "7488");  // c3 d2=0
      TRD(ta7, vaddr_, "6976"); TRD(tb7, vaddr_, "7552");  // c3 d2=1
      asm volatile("s_waitcnt lgkmcnt(0)" ::: "memory");
      __builtin_amdgcn_sched_barrier(0);
      trpair v00,v01,v10,v11,v20,v21,v30,v31;
      v00.h[0]=ta0; v00.h[1]=tb0;  v01.h[0]=ta1; v01.h[1]=tb1;
      v10.h[0]=ta2; v10.h[1]=tb2;  v11.h[0]=ta3; v11.h[1]=tb3;
      v20.h[0]=ta4; v20.h[1]=tb4;  v21.h[0]=ta5; v21.h[1]=tb5;
      v30.h[0]=ta6; v30.h[1]=tb6;  v31.h[0]=ta7; v31.h[1]=tb7;
      __builtin_amdgcn_s_setprio(1);
      o0 = __builtin_amdgcn_mfma_f32_32x32x16_bf16(v00.v, pf0.v, o0, 0,0,0);
      o1 = __builtin_amdgcn_mfma_f32_32x32x16_bf16(v01.v, pf0.v, o1, 0,0,0);
      o0 = __builtin_amdgcn_mfma_f32_32x32x16_bf16(v10.v, pf1.v, o0, 0,0,0);
      o1 = __builtin_amdgcn_mfma_f32_32x32x16_bf16(v11.v, pf1.v, o1, 0,0,0);
      o0 = __builtin_amdgcn_mfma_f32_32x32x16_bf16(v20.v, pf2.v, o0, 0,0,0);
      o1 = __builtin_amdgcn_mfma_f32_32x32x16_bf16(v21.v, pf2.v, o1, 0,0,0);
      o0 = __builtin_amdgcn_mfma_f32_32x32x16_bf16(v30.v, pf3.v, o0, 0,0,0);
      o1 = __builtin_amdgcn_mfma_f32_32x32x16_bf16(v31.v, pf3.v, o1, 0,0,0);
      __builtin_amdgcn_s_setprio(0);
    };

    // ---- prologue: fill buf0 with tile 0; preload tile 1 into regs ----
    uint4 ak0, ak1, av0, av1, bk0, bk1, bv0, bv1;
    __syncthreads();                  // prev half's epilogue scratch safe
    LOADT(0, ak0, ak1, av0, av1);
    STAGE(0, ak0, ak1, av0, av1);
    if (ktiles > 1) LOADT(1, bk0, bk1, bv0, bv1);
    __syncthreads();

    // ---- main loop: ONE barrier per tile, write-ahead into other buffer ----
    int kt = 0;
    for (;;) {
      if (kt + 1 < ktiles) STAGE(HBUF, bk0, bk1, bv0, bv1);
      if (kt + 2 < ktiles) LOADT(kt + 2, ak0, ak1, av0, av1);
      compute_tile(0, kt, vaddr0);
      __syncthreads();
      if (++kt >= ktiles) break;

      if (kt + 1 < ktiles) STAGE(0, ak0, ak1, av0, av1);
      if (kt + 2 < ktiles) LOADT(kt + 2, bk0, bk1, bv0, bv1);
      compute_tile(HBUF, kt, vaddr1);
      __syncthreads();
      if (++kt >= ktiles) break;
    }

    // ---- epilogue (scratch = buf0 region; guarded by loop's final barrier
    //      and the next half's prologue barrier) ----
    {
      uint2v t = plswap(__float_as_uint(l_part), __float_as_uint(l_part));
      l_part = __uint_as_float(t[0]) + __uint_as_float(t[1]);
    }
    const float inv = 1.0f / l_part;

#pragma unroll
    for (int k4 = 0; k4 < 4; ++k4) {
      bf16x4 pa, pb;
#pragma unroll
      for (int j = 0; j < 4; ++j) {
        pa[j] = (bf16_t)(o0[4*k4 + j] * inv);
        pb[j] = (bf16_t)(o1[4*k4 + j] * inv);
      }
      *(bf16x4*)&smem[w*2304 + l31*72 +      8*k4 + 4*hh] = pa;
      *(bf16x4*)&smem[w*2304 + l31*72 + 32 + 8*k4 + 4*hh] = pb;
    }
    u16* yp = y + ((size_t)(b*Tt + qi)) * Cc + head*64;
#pragma unroll
    for (int p = 0; p < 4; ++p) {
      bf16x8 row = *(const bf16x8*)&smem[w*2304 + l31*72 + p*16 + hh*8];
      *(bf16x8*)(yp + p*16 + hh*8) = row;
    }
  }
}

// ---------------------------------------------------------------------------
extern "C" void kernel_launch(void* const* d_in, const int* in_sizes, int n_in,
                              void* d_out, int out_size, void* d_ws, size_t ws_size,
                              hipStream_t stream) {
  const float* x      = (const float*)d_in[0];
  const float* w_attn = (const float*)d_in[1];
  const float* b_attn = (const float*)d_in[2];
  const float* w_proj = (const float*)d_in[3];
  const float* b_proj = (const float*)d_in[4];
  float* out = (float*)d_out;

  char* ws = (char*)d_ws;
  u16*   xb    = (u16*)(ws + 0);          // 16 MB
  u16*   wab   = (u16*)(ws + 16777216);   // 6 MB
  u16*   wpb   = (u16*)(ws + 23068672);   // 2 MB
  u16*   qkvb  = (u16*)(ws + 25165824);   // 48 MB
  u16*   yb    = (u16*)(ws + 75497472);   // 16 MB
  float* sbias = (float*)(ws + 92274688); // 12 KB

  // convert inputs to bf16; fold 0.125*log2e into Wq rows and bq
  cvt_f32_bf16<<<4096, 256, 0, stream>>>(x,      xb,  0, 1.0f);
  cvt_f32_bf16<<<1536, 256, 0, stream>>>(w_attn, wab, (long)Cc*Cc, QSCALE);
  cvt_f32_bf16<<<512,  256, 0, stream>>>(w_proj, wpb, 0, 1.0f);
  scale_bias<<<12, 256, 0, stream>>>(b_attn, sbias);

  // 1) QKV projection (bf16 out, q pre-scaled)
  gemm_bf16<1><<<dim3(Mtot/128, NQKV/128), 256, 0, stream>>>(
      xb, wab, sbias, (void*)qkvb, Mtot, NQKV, Cc);

  // 2) causal attention (bf16 y) — paired q-tiles, uniform 34 k-tiles/block
  attn_kernel<<<dim3(8, Bb*Hh), 256, 0, stream>>>(qkvb, yb);

  // 3) output projection (f32 out)
  gemm_bf16<0><<<dim3(Mtot/128, Cc/128), 256, 0, stream>>>(
      yb, wpb, b_proj, (void*)out, Mtot, Cc, Cc);
}